// Round 14
// baseline (372.607 us; speedup 1.0000x reference)
//
#include <hip/hip_runtime.h>
#include <hip/hip_bf16.h>
#include <stdint.h>
#include <math.h>

typedef __bf16 bf16;
typedef __bf16 bf16x8 __attribute__((ext_vector_type(8)));
typedef __bf16 bf16x4 __attribute__((ext_vector_type(4)));
typedef float  f32x4  __attribute__((ext_vector_type(4)));
typedef int    i32x4  __attribute__((ext_vector_type(4)));

#define AS_GLOBAL __attribute__((address_space(1)))
#define AS_LDS    __attribute__((address_space(3)))

__device__ __forceinline__ void gload_lds16(const void* g, void* l) {
    __builtin_amdgcn_global_load_lds((const AS_GLOBAL uint32_t*)g,
                                     (AS_LDS uint32_t*)l, 16, 0, 0);
}
__device__ __forceinline__ void cfence() { asm volatile("" ::: "memory"); }
#define BAR()    do { cfence(); __builtin_amdgcn_s_barrier(); cfence(); } while (0)
#define WAITV(n) asm volatile("s_waitcnt vmcnt(" #n ")" ::: "memory")
#define WAITL0() asm volatile("s_waitcnt lgkmcnt(0)" ::: "memory")

#define QSC 36.0f                            // q/k int8 scale
#define QDQ (1.0f / (QSC * QSC * 32.0f))     // logit dequant incl 1/sqrt(1024)

__device__ __forceinline__ int qi8(float f) {
    int q = (int)rintf(f);
    return q > 127 ? 127 : (q < -127 ? -127 : q);
}

// ---------------- convert fp32 -> bf16, 4 elems/thread ----------------
__global__ __launch_bounds__(256) void cvt_f32_to_bf16(const float* __restrict__ in,
                                                       bf16* __restrict__ out, int n4) {
    int i = blockIdx.x * 256 + threadIdx.x;
    if (i >= n4) return;
    const float4* p = (const float4*)in;
    float4 v = p[i];
    bf16x4 o;
    o[0] = (bf16)v.x; o[1] = (bf16)v.y; o[2] = (bf16)v.z; o[3] = (bf16)v.w;
    *(bf16x4*)(out + (size_t)i * 4) = o;
}

// ---- Q,K panels of QKV (bf16, ld=3072) -> int8 (scale 36), 8 elems/thread ----
__global__ __launch_bounds__(256) void cvt_qk_i8(const bf16* __restrict__ QKV,
                                                 int8_t* __restrict__ Qi8,
                                                 int8_t* __restrict__ Ki8) {
    int i = blockIdx.x * 256 + threadIdx.x;
    int base = i * 8;
    int row = base >> 11;
    int c = base & 2047;
    bf16x8 v = *(const bf16x8*)(QKV + (size_t)row * 3072 + c);
    uint32_t w0 = 0, w1 = 0;
    #pragma unroll
    for (int j = 0; j < 4; ++j) w0 |= (uint32_t)(qi8((float)v[j] * QSC) & 0xff) << (8 * j);
    #pragma unroll
    for (int j = 0; j < 4; ++j) w1 |= (uint32_t)(qi8((float)v[j + 4] * QSC) & 0xff) << (8 * j);
    int8_t* dst = (c < 1024) ? (Qi8 + (size_t)row * 1024 + c)
                             : (Ki8 + (size_t)row * 1024 + (c - 1024));
    uint2 pk; pk.x = w0; pk.y = w1;
    *(uint2*)dst = pk;
}

// ====== int8 QK^T -> bf16 E, 128x128 tile / 64KB LDS / 2 blocks/CU ======
// BK=128 bytes. 512 thr = 8 waves (2M x 4N), wave tile 64x32, 16x16x64 i8 MFMA
// (4m x 2n x 2kk = 16 MFMA/K-tile). Conflict-free read geometry (r12/r13 law):
// slot = ((kk<<2)+fg) ^ (row&7). A-tile = 16KB = 2 loads/thread (rows r0, r0+64,
// same inv-swizzled col since 64 = 0 mod 8). 2-window schedule, counted vmcnt(2):
//  W1 {stage B(t+1); 12 ds_reads; 8 MFMA m01; lgkm0; bar}
//  W2 {stage A(t+2); 8 MFMA m23; vmcnt(2) [leaves A(t+2) -> tile t+1 landed]; bar}
__global__ __launch_bounds__(512, 4) void gemmEi8(const int8_t* __restrict__ A,
                                                  const int8_t* __restrict__ B,
                                                  bf16* __restrict__ E,
                                                  int K, int ld, int ldc, int nbn) {
    __shared__ char smem[65536];   // A dbuf 2x16KB @0 | B dbuf 2x16KB @32768

    const int tid  = threadIdx.x;
    const int lane = tid & 63;
    const int wave = tid >> 6;
    const int wr   = wave >> 2;           // 0..1 -> rows wr*64
    const int wc   = wave & 3;            // 0..3 -> cols wc*32
    const int frow = lane & 15;
    const int fg   = lane >> 4;           // 0..3

    const int cpx = gridDim.x >> 3;
    const int swz = ((int)blockIdx.x & 7) * cpx + ((int)blockIdx.x >> 3);
    const int bm = swz / nbn, bn = swz % nbn;
    const int NT = K >> 7;                // 8

    const int r0 = tid >> 3;                        // 0..63
    const int c0 = ((tid & 7) ^ (r0 & 7)) << 4;     // inv-swizzled byte col
    const int8_t* Abase = A + (size_t)(bm * 128 + r0) * ld + c0;
    const int8_t* Bbase = B + (size_t)(bn * 128 + r0) * ld + c0;

    auto stA = [&](int t) {               // 128 rows x 128B = 2 loads/thread
        char* d = smem + ((t & 1) << 14) + (tid << 4);
        gload_lds16(Abase + (size_t)t * 128, d);
        gload_lds16(Abase + (size_t)64 * ld + (size_t)t * 128, d + 8192);
    };
    auto stB = [&](int t) {
        char* d = smem + 32768 + ((t & 1) << 14) + (tid << 4);
        gload_lds16(Bbase + (size_t)t * 128, d);
        gload_lds16(Bbase + (size_t)64 * ld + (size_t)t * 128, d + 8192);
    };
    auto rdA = [&](int t, int m, int kk) -> i32x4 {   // m in [0,4)
        int r = wr * 64 + m * 16 + frow;
        return *(const i32x4*)(smem + ((t & 1) << 14)
                + r * 128 + ((((kk << 2) + fg) ^ (r & 7)) << 4));
    };
    auto rdB = [&](int t, int n, int kk) -> i32x4 {   // n in [0,2)
        int r = wc * 32 + n * 16 + frow;
        return *(const i32x4*)(smem + 32768 + ((t & 1) << 14)
                + r * 128 + ((((kk << 2) + fg) ^ (r & 7)) << 4));
    };

    i32x4 acc[4][2] = {};
    i32x4 a[4][2], b[2][2];

#define MME(MO) \
    _Pragma("unroll") for (int m_ = 0; m_ < 2; ++m_) \
    _Pragma("unroll") for (int n_ = 0; n_ < 2; ++n_) \
    _Pragma("unroll") for (int k_ = 0; k_ < 2; ++k_) \
        acc[m_ + MO][n_] = __builtin_amdgcn_mfma_i32_16x16x64_i8( \
            a[m_ + MO][k_], b[n_][k_], acc[m_ + MO][n_], 0, 0, 0);

    // prologue: A(0),B(0),A(1); vmcnt(2) -> tile 0 landed
    stA(0); stB(0); stA(1);
    WAITV(2);
    BAR();

    for (int t = 0; t < NT; ++t) {
        // ---------- window 1 ----------
        if (t + 1 < NT) stB(t + 1);
        #pragma unroll
        for (int m_ = 0; m_ < 4; ++m_)
            #pragma unroll
            for (int k_ = 0; k_ < 2; ++k_) a[m_][k_] = rdA(t, m_, k_);
        #pragma unroll
        for (int n_ = 0; n_ < 2; ++n_)
            #pragma unroll
            for (int k_ = 0; k_ < 2; ++k_) b[n_][k_] = rdB(t, n_, k_);
        __builtin_amdgcn_s_setprio(1);
        MME(0);
        __builtin_amdgcn_s_setprio(0);
        WAITL0();
        BAR();
        // ---------- window 2 ----------
        if (t + 2 < NT) stA(t + 2);
        __builtin_amdgcn_s_setprio(1);
        MME(2);
        __builtin_amdgcn_s_setprio(0);
        if (t + 2 < NT)      { WAITV(2); }
        else if (t + 1 < NT) { WAITV(0); }
        BAR();
    }
#undef MME

    // epilogue: E = exp(acc*QDQ); 16x16 C/D: col=lane&15, row=(lane>>4)*4+i
    const size_t crow0 = (size_t)bm * 128 + wr * 64 + (fg << 2);
    const size_t ccol0 = (size_t)bn * 128 + wc * 32 + frow;
    #pragma unroll
    for (int m = 0; m < 4; ++m)
        #pragma unroll
        for (int n = 0; n < 2; ++n)
            #pragma unroll
            for (int i = 0; i < 4; ++i)
                E[(crow0 + m * 16 + i) * ldc + ccol0 + n * 16] =
                    (bf16)__expf((float)acc[m][n][i] * QDQ);
}

// ====== PV GEMM: 128x128 tile / 64KB LDS / 2 blocks/CU, bf16 16x16x32, split-K=2 ======
// Same geometry/schedule as gemmEi8 above, bf16 frags (identical byte-level
// slot math: lane frag = 16B at slot ((kk<<2)+fg)^(row&7); rows 128B = BK=64 bf16).
__global__ __launch_bounds__(512, 4) void gemmPV(const bf16* __restrict__ A,
                                                 const bf16* __restrict__ B,
                                                 float* __restrict__ C,
                                                 float* __restrict__ C2,
                                                 int K, int lda, int ldb, int ldc,
                                                 int nbn) {
    __shared__ char smem[65536];   // A dbuf 2x16KB @0 | B dbuf 2x16KB @32768

    const int tid  = threadIdx.x;
    const int lane = tid & 63;
    const int wave = tid >> 6;
    const int wr   = wave >> 2;
    const int wc   = wave & 3;
    const int frow = lane & 15;
    const int fg   = lane >> 4;

    const int cpx = gridDim.x >> 3;
    const int swz = ((int)blockIdx.x & 7) * cpx + ((int)blockIdx.x >> 3);
    int id = swz;
    const int s = id & 1; id >>= 1;
    const int bm = id / nbn, bn = id % nbn;
    const int NT = K >> 6;                // 64
    const size_t koff = (size_t)s * K;
    float* Cp = (s == 1) ? C2 : C;

    const int r0 = tid >> 3;
    const int c0 = ((tid & 7) ^ (r0 & 7)) << 3;     // inv-swizzled col (bf16 elems)
    const bf16* Abase = A + (size_t)(bm * 128 + r0) * lda + c0 + koff;
    const bf16* Bbase = B + (size_t)(bn * 128 + r0) * ldb + c0 + koff;

    auto stA = [&](int t) {
        char* d = smem + ((t & 1) << 14) + (tid << 4);
        gload_lds16(Abase + (size_t)t * 64, d);
        gload_lds16(Abase + (size_t)64 * lda + (size_t)t * 64, d + 8192);
    };
    auto stB = [&](int t) {
        char* d = smem + 32768 + ((t & 1) << 14) + (tid << 4);
        gload_lds16(Bbase + (size_t)t * 64, d);
        gload_lds16(Bbase + (size_t)64 * ldb + (size_t)t * 64, d + 8192);
    };
    auto rdA = [&](int t, int m, int kk) -> bf16x8 {
        int r = wr * 64 + m * 16 + frow;
        return *(const bf16x8*)(smem + ((t & 1) << 14)
                + r * 128 + ((((kk << 2) + fg) ^ (r & 7)) << 4));
    };
    auto rdB = [&](int t, int n, int kk) -> bf16x8 {
        int r = wc * 32 + n * 16 + frow;
        return *(const bf16x8*)(smem + 32768 + ((t & 1) << 14)
                + r * 128 + ((((kk << 2) + fg) ^ (r & 7)) << 4));
    };

    f32x4 acc[4][2] = {};
    bf16x8 a[4][2], b[2][2];

#define MMP(MO) \
    _Pragma("unroll") for (int m_ = 0; m_ < 2; ++m_) \
    _Pragma("unroll") for (int n_ = 0; n_ < 2; ++n_) \
    _Pragma("unroll") for (int k_ = 0; k_ < 2; ++k_) \
        acc[m_ + MO][n_] = __builtin_amdgcn_mfma_f32_16x16x32_bf16( \
            a[m_ + MO][k_], b[n_][k_], acc[m_ + MO][n_], 0, 0, 0);

    stA(0); stB(0); stA(1);
    WAITV(2);
    BAR();

    for (int t = 0; t < NT; ++t) {
        // ---------- window 1 ----------
        if (t + 1 < NT) stB(t + 1);
        #pragma unroll
        for (int m_ = 0; m_ < 4; ++m_)
            #pragma unroll
            for (int k_ = 0; k_ < 2; ++k_) a[m_][k_] = rdA(t, m_, k_);
        #pragma unroll
        for (int n_ = 0; n_ < 2; ++n_)
            #pragma unroll
            for (int k_ = 0; k_ < 2; ++k_) b[n_][k_] = rdB(t, n_, k_);
        __builtin_amdgcn_s_setprio(1);
        MMP(0);
        __builtin_amdgcn_s_setprio(0);
        WAITL0();
        BAR();
        // ---------- window 2 ----------
        if (t + 2 < NT) stA(t + 2);
        __builtin_amdgcn_s_setprio(1);
        MMP(2);
        __builtin_amdgcn_s_setprio(0);
        if (t + 2 < NT)      { WAITV(2); }
        else if (t + 1 < NT) { WAITV(0); }
        BAR();
    }
#undef MMP

    // epilogue: 16x16 C/D layout, raw f32 acc
    const size_t crow0 = (size_t)bm * 128 + wr * 64 + (fg << 2);
    const size_t ccol0 = (size_t)bn * 128 + wc * 32 + frow;
    #pragma unroll
    for (int m = 0; m < 4; ++m)
        #pragma unroll
        for (int n = 0; n < 2; ++n)
            #pragma unroll
            for (int i = 0; i < 4; ++i)
                Cp[(crow0 + m * 16 + i) * ldc + ccol0 + n * 16] = acc[m][n][i];
}

// ====== 2-window/K-tile bf16 GEMM (r7/r10 verified) — QKV projection only ======
template<typename CT, int BN>
__global__ __launch_bounds__(512, 2) void gemmW(const bf16* __restrict__ A,
                                                const bf16* __restrict__ B,
                                                CT* __restrict__ C,
                                                int K, int lda, int ldb, int ldc,
                                                int nbn) {
    constexpr int NBH = BN / 128;
    constexpr int NR  = BN / 64;
    constexpr int NHF = NR / 2;
    __shared__ char smem[65536 + NBH * 32768];

    const int tid  = threadIdx.x;
    const int lane = tid & 63;
    const int wave = tid >> 6;
    const int wr   = wave >> 2;
    const int wc   = wave & 3;
    const int frow = lane & 15;
    const int fg   = lane >> 4;

    const int cpx = gridDim.x >> 3;
    const int swz = ((int)blockIdx.x & 7) * cpx + ((int)blockIdx.x >> 3);
    const int bm = swz / nbn, bn = swz % nbn;
    const int NT = K >> 6;

    const int r0 = tid >> 3;
    const int c0 = ((tid & 7) ^ (r0 & 7)) << 3;
    const bf16* Abase = A + (size_t)(bm * 256 + r0) * lda + c0;
    const bf16* Bbase = B + (size_t)(bn * BN + r0) * ldb + c0;

    auto stA = [&](int t, int h) {
        char* d = smem + ((t & 1) << 15) + (h << 14) + (tid << 4);
        gload_lds16(Abase + ((size_t)(h * 128)      ) * lda + t * 64, d);
        gload_lds16(Abase + ((size_t)(h * 128) + 64 ) * lda + t * 64, d + 8192);
    };
    auto stB = [&](int t, int h) {
        char* d = smem + 65536 + (t & 1) * (NBH * 16384) + (h << 14) + (tid << 4);
        gload_lds16(Bbase + ((size_t)(h * 128)      ) * ldb + t * 64, d);
        gload_lds16(Bbase + ((size_t)(h * 128) + 64 ) * ldb + t * 64, d + 8192);
    };
    auto rdA = [&](int t, int m, int kk) -> bf16x8 {
        int r = m * 16 + frow;
        return *(const bf16x8*)(smem + ((t & 1) << 15) + (wr << 14)
                + r * 128 + ((((kk << 2) + fg) ^ (frow & 7)) << 4));
    };
    auto rdB = [&](int t, int n, int kk) -> bf16x8 {
        int br = wc * (BN / 4) + n * 16 + frow;
        return *(const bf16x8*)(smem + 65536 + (t & 1) * (NBH * 16384) + ((br >> 7) << 14)
                + (br & 127) * 128 + ((((kk << 2) + fg) ^ (frow & 7)) << 4));
    };

    f32x4 acc[8][NR] = {};
    bf16x8 aLo[4][2], aHi[4][2], bLo[NHF][2], bHi[NHF][2];

#define MMQ(MO, NO, AARR, BARR) \
    _Pragma("unroll") for (int m_ = 0; m_ < 4; ++m_) \
    _Pragma("unroll") for (int n_ = 0; n_ < NHF; ++n_) \
    _Pragma("unroll") for (int k_ = 0; k_ < 2; ++k_) \
        acc[m_ + MO][n_ + NO] = __builtin_amdgcn_mfma_f32_16x16x32_bf16( \
            AARR[m_][k_], BARR[n_][k_], acc[m_ + MO][n_ + NO], 0, 0, 0);

    stA(0, 0); stA(0, 1);
    stB(0, 0); if constexpr (NBH == 2) stB(0, 1);
    stA(1, 0); stA(1, 1);
    if constexpr (NBH == 2) { stB(1, 0); WAITV(6); } else { WAITV(4); }
    BAR();

    for (int t = 0; t < NT; ++t) {
        if (t + 1 < NT) stB(t + 1, NBH - 1);
        #pragma unroll
        for (int m_ = 0; m_ < 4; ++m_) { aLo[m_][0] = rdA(t, m_, 0); aLo[m_][1] = rdA(t, m_, 1); }
        #pragma unroll
        for (int n_ = 0; n_ < NHF; ++n_) { bLo[n_][0] = rdB(t, n_, 0); bLo[n_][1] = rdB(t, n_, 1); }
        #pragma unroll
        for (int n_ = 0; n_ < NHF; ++n_) { bHi[n_][0] = rdB(t, NHF + n_, 0); bHi[n_][1] = rdB(t, NHF + n_, 1); }
        #pragma unroll
        for (int m_ = 0; m_ < 4; ++m_) { aHi[m_][0] = rdA(t, 4 + m_, 0); aHi[m_][1] = rdA(t, 4 + m_, 1); }
        __builtin_amdgcn_s_setprio(1);
        MMQ(0, 0, aLo, bLo);
        MMQ(0, NHF, aLo, bHi);
        __builtin_amdgcn_s_setprio(0);
        WAITL0();
        BAR();
        if (t + 2 < NT) {
            stA(t + 2, 0); stA(t + 2, 1);
            if constexpr (NBH == 2) stB(t + 2, 0);
        }
        __builtin_amdgcn_s_setprio(1);
        MMQ(4, NHF, aHi, bHi);
        MMQ(4, 0, aHi, bLo);
        __builtin_amdgcn_s_setprio(0);
        if (t + 2 < NT) {
            if constexpr (NBH == 2) WAITV(6); else WAITV(4);
        } else if (t + 1 < NT) {
            WAITV(0);
        }
        BAR();
    }
#undef MMQ

    const size_t crow0 = (size_t)bm * 256 + wr * 128 + (fg << 2);
    const size_t ccol0 = (size_t)bn * BN + wc * (BN / 4) + frow;
    #pragma unroll
    for (int m = 0; m < 8; ++m)
        #pragma unroll
        for (int n = 0; n < NR; ++n)
            #pragma unroll
            for (int i = 0; i < 4; ++i)
                C[(crow0 + m * 16 + i) * ldc + ccol0 + n * 16] = (CT)(acc[m][n][i]);
}

// ------- rowsum of E [rows x 8192] bf16 -> inv[row] = 1/sum -------
__global__ __launch_bounds__(256) void rowsum_inv(const bf16* __restrict__ E,
                                                  float* __restrict__ inv, int cols) {
    __shared__ float red[4];
    const int tid = threadIdx.x;
    const bf16* er = E + (size_t)blockIdx.x * cols;
    float s = 0.f;
    #pragma unroll
    for (int it = 0; it < 4; ++it) {
        bf16x8 v = *(const bf16x8*)(er + it * 2048 + tid * 8);
        #pragma unroll
        for (int j = 0; j < 8; ++j) s += (float)v[j];
    }
    #pragma unroll
    for (int o = 32; o; o >>= 1) s += __shfl_xor(s, o);
    if ((tid & 63) == 0) red[tid >> 6] = s;
    __syncthreads();
    if (tid == 0) inv[blockIdx.x] = 1.0f / (red[0] + red[1] + red[2] + red[3]);
}

// ------- out[i] = (out[i] + part[i]) * inv[row], float4 -------
__global__ __launch_bounds__(256) void add_scale(float* __restrict__ out,
                                                 const float* __restrict__ part,
                                                 const float* __restrict__ inv, int n4) {
    int i = blockIdx.x * 256 + threadIdx.x;
    if (i >= n4) return;
    const float sc = inv[i >> 8];
    float4 a = ((const float4*)out)[i];
    float4 b = ((const float4*)part)[i];
    a.x = (a.x + b.x) * sc; a.y = (a.y + b.y) * sc;
    a.z = (a.z + b.z) * sc; a.w = (a.w + b.w) * sc;
    ((float4*)out)[i] = a;
}

// ------- bf16 transpose with input row stride: VT[c][r] = V[r*ld + c] -------
__global__ __launch_bounds__(256) void transpose_bf16(const ushort* __restrict__ V,
                                                      ushort* __restrict__ VT,
                                                      int R, int ld) {
    __shared__ ushort tile[32][33];
    const int tx = threadIdx.x, ty = threadIdx.y;
    const int r0 = blockIdx.y * 32, c0 = blockIdx.x * 32;
    #pragma unroll
    for (int i = 0; i < 32; i += 8)
        tile[ty + i][tx] = V[(size_t)(r0 + ty + i) * ld + c0 + tx];
    __syncthreads();
    #pragma unroll
    for (int i = 0; i < 32; i += 8)
        VT[(size_t)(c0 + ty + i) * R + r0 + tx] = tile[tx][ty + i];
}

extern "C" void kernel_launch(void* const* d_in, const int* in_sizes, int n_in,
                              void* d_out, int out_size, void* d_ws, size_t ws_size,
                              hipStream_t stream) {
    const float* h  = (const float*)d_in[0];
    const float* wq = (const float*)d_in[1];
    const float* wk = (const float*)d_in[2];
    const float* wv = (const float*)d_in[3];
    float* out = (float*)d_out;

    char* ws = (char*)d_ws;
    bf16*   h_bf = (bf16*)(ws);                         // 16 MB [8192 x 1024]
    bf16*   wcat = (bf16*)(ws + (16ull << 20));         //  6 MB [3072 x 1024]
    bf16*   QKV  = (bf16*)(ws + (22ull << 20));         // 48 MB [8192 x 3072]
    bf16*   VT   = (bf16*)(ws + (70ull << 20));         // 16 MB [1024 x 8192]
    bf16*   E    = (bf16*)(ws + (86ull << 20));         // 128 MB [8192 x 8192]
    int8_t* Qi8  = (int8_t*)(ws);                       //  8 MB (h_bf dead post-QKV)
    int8_t* Ki8  = (int8_t*)(ws + (8ull << 20));        //  8 MB
    float*  Pv   = (float*)(ws);                        // 32 MB (Qi8/Ki8 dead by PV)
    float*  invp = (float*)(ws + (33ull << 20));        // 32 KB (QKV dead by rowsum)

    // 1) inputs -> bf16 (weights concatenated [3072,1024])
    cvt_f32_to_bf16<<<8192, 256, 0, stream>>>(h,  h_bf, (8192 * 1024) / 4);
    cvt_f32_to_bf16<<<1024, 256, 0, stream>>>(wq, wcat,               (1024 * 1024) / 4);
    cvt_f32_to_bf16<<<1024, 256, 0, stream>>>(wk, wcat + 1024 * 1024, (1024 * 1024) / 4);
    cvt_f32_to_bf16<<<1024, 256, 0, stream>>>(wv, wcat + 2048 * 1024, (1024 * 1024) / 4);

    // 2) QKV = h @ wcat^T : [8192 x 3072], bf16 GEMM, grid 384
    gemmW<bf16, 256><<<384, 512, 0, stream>>>(h_bf, wcat, QKV,
                                              1024, 1024, 1024, 3072, 12);

    // 3) Q,K -> int8 (scale 36)
    cvt_qk_i8<<<8192, 256, 0, stream>>>(QKV, Qi8, Ki8);

    // 4) VT = V^T, bf16 (V = QKV[:, 2048:3072])
    transpose_bf16<<<dim3(32, 256), dim3(32, 8), 0, stream>>>(
        (const ushort*)(QKV + 2048), (ushort*)VT, 8192, 3072);

    // 5) E = exp((Qi8 . Ki8)/41472), 128x128 tile @ 2 blocks/CU, grid 64x64 = 4096
    gemmEi8<<<4096, 512, 0, stream>>>(Qi8, Ki8, E, 1024, 1024, 8192, 64);

    // 6) inv[row] = 1 / rowsum(E)
    rowsum_inv<<<8192, 256, 0, stream>>>(E, invp, 8192);

    // 7) P = E @ VT^T, 128x128 tile @ 2 blocks/CU, split-K=2, grid 64x8x2 = 1024
    gemmPV<<<1024, 512, 0, stream>>>(E, VT, out, Pv,
                                     4096, 8192, 8192, 1024, 8);

    // 8) out = (P0 + P1) * inv[row]
    add_scale<<<8192, 256, 0, stream>>>(out, Pv, invp, (8192 * 1024) / 4);
}

// Round 15
// 340.416 us; speedup vs baseline: 1.0946x; 1.0946x over previous
//
#include <hip/hip_runtime.h>
#include <hip/hip_bf16.h>
#include <stdint.h>
#include <math.h>

typedef __bf16 bf16;
typedef __bf16 bf16x8 __attribute__((ext_vector_type(8)));
typedef __bf16 bf16x4 __attribute__((ext_vector_type(4)));
typedef float  f32x4  __attribute__((ext_vector_type(4)));
typedef int    i32x4  __attribute__((ext_vector_type(4)));

#define AS_GLOBAL __attribute__((address_space(1)))
#define AS_LDS    __attribute__((address_space(3)))

__device__ __forceinline__ void gload_lds16(const void* g, void* l) {
    __builtin_amdgcn_global_load_lds((const AS_GLOBAL uint32_t*)g,
                                     (AS_LDS uint32_t*)l, 16, 0, 0);
}
__device__ __forceinline__ void cfence() { asm volatile("" ::: "memory"); }
#define BAR()    do { cfence(); __builtin_amdgcn_s_barrier(); cfence(); } while (0)
#define WAITV(n) asm volatile("s_waitcnt vmcnt(" #n ")" ::: "memory")
#define WAITL0() asm volatile("s_waitcnt lgkmcnt(0)" ::: "memory")

#define QSC 36.0f                            // q/k int8 scale
#define QDQ (1.0f / (QSC * QSC * 32.0f))     // logit dequant incl 1/sqrt(1024)

__device__ __forceinline__ int qi8(float f) {
    int q = (int)rintf(f);
    return q > 127 ? 127 : (q < -127 ? -127 : q);
}

// ---------------- convert fp32 -> bf16, 4 elems/thread ----------------
__global__ __launch_bounds__(256) void cvt_f32_to_bf16(const float* __restrict__ in,
                                                       bf16* __restrict__ out, int n4) {
    int i = blockIdx.x * 256 + threadIdx.x;
    if (i >= n4) return;
    const float4* p = (const float4*)in;
    float4 v = p[i];
    bf16x4 o;
    o[0] = (bf16)v.x; o[1] = (bf16)v.y; o[2] = (bf16)v.z; o[3] = (bf16)v.w;
    *(bf16x4*)(out + (size_t)i * 4) = o;
}

// ====== 2-window/K-tile bf16 GEMM (r7/r10/r13 verified): C = A * B^T ======
// EPI=0: CT out (+split-K).  EPI=1: QKV projection epilogue — col panel
// [0,1024) -> Qi8 (int8, scale 36), [1024,2048) -> Ki8, [2048,3072) -> Vb bf16
// (compact ld=1024). Each 256-col block tile lies in exactly one panel.
template<typename CT, int BN, int SPLIT, int EPI>
__global__ __launch_bounds__(512, 2) void gemmW(const bf16* __restrict__ A,
                                                const bf16* __restrict__ B,
                                                CT* __restrict__ C,
                                                CT* __restrict__ C2,
                                                int8_t* __restrict__ q8,
                                                int8_t* __restrict__ k8,
                                                bf16* __restrict__ vb,
                                                int K, int lda, int ldb, int ldc,
                                                int nbn) {
    constexpr int NBH = BN / 128;
    constexpr int NR  = BN / 64;
    constexpr int NHF = NR / 2;
    __shared__ char smem[65536 + NBH * 32768];

    const int tid  = threadIdx.x;
    const int lane = tid & 63;
    const int wave = tid >> 6;
    const int wr   = wave >> 2;
    const int wc   = wave & 3;
    const int frow = lane & 15;
    const int fg   = lane >> 4;

    const int cpx = gridDim.x >> 3;
    const int swz = ((int)blockIdx.x & 7) * cpx + ((int)blockIdx.x >> 3);
    int id = swz, s = 0;
    if (SPLIT == 2) { s = id & 1; id >>= 1; }
    const int bm = id / nbn, bn = id % nbn;
    const int NT = K >> 6;
    const size_t koff = (size_t)s * K;
    CT* Cp = (SPLIT == 2 && s == 1) ? C2 : C;

    const int r0 = tid >> 3;
    const int c0 = ((tid & 7) ^ (r0 & 7)) << 3;
    const bf16* Abase = A + (size_t)(bm * 256 + r0) * lda + c0 + koff;
    const bf16* Bbase = B + (size_t)(bn * BN + r0) * ldb + c0 + koff;

    auto stA = [&](int t, int h) {
        char* d = smem + ((t & 1) << 15) + (h << 14) + (tid << 4);
        gload_lds16(Abase + ((size_t)(h * 128)      ) * lda + t * 64, d);
        gload_lds16(Abase + ((size_t)(h * 128) + 64 ) * lda + t * 64, d + 8192);
    };
    auto stB = [&](int t, int h) {
        char* d = smem + 65536 + (t & 1) * (NBH * 16384) + (h << 14) + (tid << 4);
        gload_lds16(Bbase + ((size_t)(h * 128)      ) * ldb + t * 64, d);
        gload_lds16(Bbase + ((size_t)(h * 128) + 64 ) * ldb + t * 64, d + 8192);
    };
    auto rdA = [&](int t, int m, int kk) -> bf16x8 {
        int r = m * 16 + frow;
        return *(const bf16x8*)(smem + ((t & 1) << 15) + (wr << 14)
                + r * 128 + ((((kk << 2) + fg) ^ (frow & 7)) << 4));
    };
    auto rdB = [&](int t, int n, int kk) -> bf16x8 {
        int br = wc * (BN / 4) + n * 16 + frow;
        return *(const bf16x8*)(smem + 65536 + (t & 1) * (NBH * 16384) + ((br >> 7) << 14)
                + (br & 127) * 128 + ((((kk << 2) + fg) ^ (frow & 7)) << 4));
    };

    f32x4 acc[8][NR] = {};
    bf16x8 aLo[4][2], aHi[4][2], bLo[NHF][2], bHi[NHF][2];

#define MMQ(MO, NO, AARR, BARR) \
    _Pragma("unroll") for (int m_ = 0; m_ < 4; ++m_) \
    _Pragma("unroll") for (int n_ = 0; n_ < NHF; ++n_) \
    _Pragma("unroll") for (int k_ = 0; k_ < 2; ++k_) \
        acc[m_ + MO][n_ + NO] = __builtin_amdgcn_mfma_f32_16x16x32_bf16( \
            AARR[m_][k_], BARR[n_][k_], acc[m_ + MO][n_ + NO], 0, 0, 0);

    stA(0, 0); stA(0, 1);
    stB(0, 0); if constexpr (NBH == 2) stB(0, 1);
    stA(1, 0); stA(1, 1);
    if constexpr (NBH == 2) { stB(1, 0); WAITV(6); } else { WAITV(4); }
    BAR();

    for (int t = 0; t < NT; ++t) {
        if (t + 1 < NT) stB(t + 1, NBH - 1);
        #pragma unroll
        for (int m_ = 0; m_ < 4; ++m_) { aLo[m_][0] = rdA(t, m_, 0); aLo[m_][1] = rdA(t, m_, 1); }
        #pragma unroll
        for (int n_ = 0; n_ < NHF; ++n_) { bLo[n_][0] = rdB(t, n_, 0); bLo[n_][1] = rdB(t, n_, 1); }
        #pragma unroll
        for (int n_ = 0; n_ < NHF; ++n_) { bHi[n_][0] = rdB(t, NHF + n_, 0); bHi[n_][1] = rdB(t, NHF + n_, 1); }
        #pragma unroll
        for (int m_ = 0; m_ < 4; ++m_) { aHi[m_][0] = rdA(t, 4 + m_, 0); aHi[m_][1] = rdA(t, 4 + m_, 1); }
        __builtin_amdgcn_s_setprio(1);
        MMQ(0, 0, aLo, bLo);
        MMQ(0, NHF, aLo, bHi);
        __builtin_amdgcn_s_setprio(0);
        WAITL0();
        BAR();
        if (t + 2 < NT) {
            stA(t + 2, 0); stA(t + 2, 1);
            if constexpr (NBH == 2) stB(t + 2, 0);
        }
        __builtin_amdgcn_s_setprio(1);
        MMQ(4, NHF, aHi, bHi);
        MMQ(4, 0, aHi, bLo);
        __builtin_amdgcn_s_setprio(0);
        if (t + 2 < NT) {
            if constexpr (NBH == 2) WAITV(6); else WAITV(4);
        } else if (t + 1 < NT) {
            WAITV(0);
        }
        BAR();
    }
#undef MMQ

    // epilogue: C/D layout col = lane&15, row = (lane>>4)*4 + i
    const size_t crow0 = (size_t)bm * 256 + wr * 128 + (fg << 2);
    const size_t ccol0 = (size_t)bn * BN + wc * (BN / 4) + frow;
    if constexpr (EPI == 1) {
        // block-uniform panel select (BN=256 divides 1024)
        const int panel = (int)(ccol0 >> 10);            // 0=Q, 1=K, 2=V
        const size_t pcol0 = ccol0 & 1023;
        #pragma unroll
        for (int m = 0; m < 8; ++m)
            #pragma unroll
            for (int n = 0; n < NR; ++n)
                #pragma unroll
                for (int i = 0; i < 4; ++i) {
                    float v = acc[m][n][i];
                    size_t row = crow0 + m * 16 + i;
                    size_t col = pcol0 + n * 16;
                    if (panel == 0)
                        q8[row * 1024 + col] = (int8_t)qi8(v * QSC);
                    else if (panel == 1)
                        k8[row * 1024 + col] = (int8_t)qi8(v * QSC);
                    else
                        vb[row * 1024 + col] = (bf16)v;
                }
    } else {
        #pragma unroll
        for (int m = 0; m < 8; ++m)
            #pragma unroll
            for (int n = 0; n < NR; ++n)
                #pragma unroll
                for (int i = 0; i < 4; ++i)
                    Cp[(crow0 + m * 16 + i) * ldc + ccol0 + n * 16] = (CT)(acc[m][n][i]);
    }
}

// ====== int8 QK^T -> bf16 E = exp(acc/41472), 16x16x64 i8 MFMA (r13 verified) ======
// Conflict-free read geometry (r12 law): slot = ((kk<<2)+fg) ^ (row&7) -> 0 conflicts.
__global__ __launch_bounds__(512, 2) void gemmEi8(const int8_t* __restrict__ A,
                                                  const int8_t* __restrict__ B,
                                                  bf16* __restrict__ E,
                                                  int K, int ld, int ldc, int nbn) {
    __shared__ char smem[131072];   // A dbuf 2x32KB @0 | B dbuf 2x32KB @65536

    const int tid  = threadIdx.x;
    const int lane = tid & 63;
    const int wave = tid >> 6;
    const int wr   = wave >> 2;           // 0..1
    const int wc   = wave & 3;            // 0..3
    const int frow = lane & 15;
    const int fg   = lane >> 4;           // 0..3

    const int cpx = gridDim.x >> 3;
    const int swz = ((int)blockIdx.x & 7) * cpx + ((int)blockIdx.x >> 3);
    const int bm = swz / nbn, bn = swz % nbn;
    const int NT = K >> 7;                // 8

    const int r0 = tid >> 3;
    const int c0 = ((tid & 7) ^ (r0 & 7)) << 4;     // inv-swizzled byte col
    const int8_t* Abase = A + (size_t)(bm * 256 + r0) * ld + c0;
    const int8_t* Bbase = B + (size_t)(bn * 256 + r0) * ld + c0;

    auto stA = [&](int t, int h) {
        char* d = smem + ((t & 1) << 15) + (h << 14) + (tid << 4);
        gload_lds16(Abase + ((size_t)(h * 128)     ) * ld + t * 128, d);
        gload_lds16(Abase + ((size_t)(h * 128) + 64) * ld + t * 128, d + 8192);
    };
    auto stB = [&](int t, int h) {
        char* d = smem + 65536 + ((t & 1) << 15) + (h << 14) + (tid << 4);
        gload_lds16(Bbase + ((size_t)(h * 128)     ) * ld + t * 128, d);
        gload_lds16(Bbase + ((size_t)(h * 128) + 64) * ld + t * 128, d + 8192);
    };
    auto rdA = [&](int t, int m, int kk) -> i32x4 {   // m in [0,8)
        int r = m * 16 + frow;
        return *(const i32x4*)(smem + ((t & 1) << 15) + (wr << 14)
                + r * 128 + ((((kk << 2) + fg) ^ (frow & 7)) << 4));
    };
    auto rdB = [&](int t, int n, int kk) -> i32x4 {   // n in [0,4)
        int br = wc * 64 + n * 16 + frow;
        return *(const i32x4*)(smem + 65536 + ((t & 1) << 15) + ((br >> 7) << 14)
                + (br & 127) * 128 + ((((kk << 2) + fg) ^ (frow & 7)) << 4));
    };

    i32x4 acc[8][4] = {};
    i32x4 aLo[4][2], aHi[4][2], bLo[2][2], bHi[2][2];

#define MMQ(MO, NO, AARR, BARR) \
    _Pragma("unroll") for (int m_ = 0; m_ < 4; ++m_) \
    _Pragma("unroll") for (int n_ = 0; n_ < 2; ++n_) \
    _Pragma("unroll") for (int k_ = 0; k_ < 2; ++k_) \
        acc[m_ + MO][n_ + NO] = __builtin_amdgcn_mfma_i32_16x16x64_i8( \
            AARR[m_][k_], BARR[n_][k_], acc[m_ + MO][n_ + NO], 0, 0, 0);

    stA(0, 0); stA(0, 1);
    stB(0, 0); stB(0, 1);
    stA(1, 0); stA(1, 1);
    stB(1, 0); WAITV(6);
    BAR();

    for (int t = 0; t < NT; ++t) {
        if (t + 1 < NT) stB(t + 1, 1);
        #pragma unroll
        for (int m_ = 0; m_ < 4; ++m_) { aLo[m_][0] = rdA(t, m_, 0); aLo[m_][1] = rdA(t, m_, 1); }
        #pragma unroll
        for (int n_ = 0; n_ < 2; ++n_) { bLo[n_][0] = rdB(t, n_, 0); bLo[n_][1] = rdB(t, n_, 1); }
        #pragma unroll
        for (int n_ = 0; n_ < 2; ++n_) { bHi[n_][0] = rdB(t, 2 + n_, 0); bHi[n_][1] = rdB(t, 2 + n_, 1); }
        #pragma unroll
        for (int m_ = 0; m_ < 4; ++m_) { aHi[m_][0] = rdA(t, 4 + m_, 0); aHi[m_][1] = rdA(t, 4 + m_, 1); }
        __builtin_amdgcn_s_setprio(1);
        MMQ(0, 0, aLo, bLo);
        MMQ(0, 2, aLo, bHi);
        __builtin_amdgcn_s_setprio(0);
        WAITL0();
        BAR();
        if (t + 2 < NT) { stA(t + 2, 0); stA(t + 2, 1); stB(t + 2, 0); }
        __builtin_amdgcn_s_setprio(1);
        MMQ(4, 2, aHi, bHi);
        MMQ(4, 0, aHi, bLo);
        __builtin_amdgcn_s_setprio(0);
        if (t + 2 < NT)      { WAITV(6); }
        else if (t + 1 < NT) { WAITV(0); }
        BAR();
    }
#undef MMQ

    // epilogue: E = exp(acc * QDQ), 16x16 C/D layout
    const size_t crow0 = (size_t)bm * 256 + wr * 128 + (fg << 2);
    const size_t ccol0 = (size_t)bn * 256 + wc * 64 + frow;
    #pragma unroll
    for (int m = 0; m < 8; ++m)
        #pragma unroll
        for (int n = 0; n < 4; ++n)
            #pragma unroll
            for (int i = 0; i < 4; ++i)
                E[(crow0 + m * 16 + i) * ldc + ccol0 + n * 16] =
                    (bf16)__expf((float)acc[m][n][i] * QDQ);
}

// ------- rowsum of E [rows x 8192] bf16 -> inv[row] = 1/sum -------
__global__ __launch_bounds__(256) void rowsum_inv(const bf16* __restrict__ E,
                                                  float* __restrict__ inv, int cols) {
    __shared__ float red[4];
    const int tid = threadIdx.x;
    const bf16* er = E + (size_t)blockIdx.x * cols;
    float s = 0.f;
    #pragma unroll
    for (int it = 0; it < 4; ++it) {
        bf16x8 v = *(const bf16x8*)(er + it * 2048 + tid * 8);
        #pragma unroll
        for (int j = 0; j < 8; ++j) s += (float)v[j];
    }
    #pragma unroll
    for (int o = 32; o; o >>= 1) s += __shfl_xor(s, o);
    if ((tid & 63) == 0) red[tid >> 6] = s;
    __syncthreads();
    if (tid == 0) inv[blockIdx.x] = 1.0f / (red[0] + red[1] + red[2] + red[3]);
}

// ------- out[i] = (out[i] + part[i]) * inv[row], float4 -------
__global__ __launch_bounds__(256) void add_scale(float* __restrict__ out,
                                                 const float* __restrict__ part,
                                                 const float* __restrict__ inv, int n4) {
    int i = blockIdx.x * 256 + threadIdx.x;
    if (i >= n4) return;
    const float sc = inv[i >> 8];
    float4 a = ((const float4*)out)[i];
    float4 b = ((const float4*)part)[i];
    a.x = (a.x + b.x) * sc; a.y = (a.y + b.y) * sc;
    a.z = (a.z + b.z) * sc; a.w = (a.w + b.w) * sc;
    ((float4*)out)[i] = a;
}

// ------- bf16 transpose with input row stride: VT[c][r] = V[r*ld + c] -------
__global__ __launch_bounds__(256) void transpose_bf16(const ushort* __restrict__ V,
                                                      ushort* __restrict__ VT,
                                                      int R, int ld) {
    __shared__ ushort tile[32][33];
    const int tx = threadIdx.x, ty = threadIdx.y;
    const int r0 = blockIdx.y * 32, c0 = blockIdx.x * 32;
    #pragma unroll
    for (int i = 0; i < 32; i += 8)
        tile[ty + i][tx] = V[(size_t)(r0 + ty + i) * ld + c0 + tx];
    __syncthreads();
    #pragma unroll
    for (int i = 0; i < 32; i += 8)
        VT[(size_t)(c0 + ty + i) * R + r0 + tx] = tile[tx][ty + i];
}

extern "C" void kernel_launch(void* const* d_in, const int* in_sizes, int n_in,
                              void* d_out, int out_size, void* d_ws, size_t ws_size,
                              hipStream_t stream) {
    const float* h  = (const float*)d_in[0];
    const float* wq = (const float*)d_in[1];
    const float* wk = (const float*)d_in[2];
    const float* wv = (const float*)d_in[3];
    float* out = (float*)d_out;

    char* ws = (char*)d_ws;
    bf16*   h_bf = (bf16*)(ws);                         // 16 MB [8192 x 1024]
    bf16*   wcat = (bf16*)(ws + (16ull << 20));         //  6 MB [3072 x 1024]
    int8_t* Qi8  = (int8_t*)(ws + (22ull << 20));       //  8 MB [8192 x 1024]
    int8_t* Ki8  = (int8_t*)(ws + (30ull << 20));       //  8 MB
    bf16*   Vb   = (bf16*)(ws + (38ull << 20));         // 16 MB [8192 x 1024]
    bf16*   VT   = (bf16*)(ws + (54ull << 20));         // 16 MB [1024 x 8192]
    bf16*   E    = (bf16*)(ws + (70ull << 20));         // 128 MB [8192 x 8192]
    float*  Pv   = (float*)(ws);                        // 32 MB (h_bf/wcat/Qi8/Ki8 dead by PV)
    float*  invp = (float*)(ws + (198ull << 20));       // 32 KB

    // 1) inputs -> bf16 (weights concatenated [3072,1024])
    cvt_f32_to_bf16<<<8192, 256, 0, stream>>>(h,  h_bf, (8192 * 1024) / 4);
    cvt_f32_to_bf16<<<1024, 256, 0, stream>>>(wq, wcat,               (1024 * 1024) / 4);
    cvt_f32_to_bf16<<<1024, 256, 0, stream>>>(wk, wcat + 1024 * 1024, (1024 * 1024) / 4);
    cvt_f32_to_bf16<<<1024, 256, 0, stream>>>(wv, wcat + 2048 * 1024, (1024 * 1024) / 4);

    // 2) fused QKV projection: Q,K -> int8 (scale 36), V -> compact bf16, grid 384
    gemmW<bf16, 256, 1, 1><<<384, 512, 0, stream>>>(h_bf, wcat, nullptr, nullptr,
                                                    Qi8, Ki8, Vb,
                                                    1024, 1024, 1024, 1024, 12);

    // 3) VT = Vb^T (ld = 1024)
    transpose_bf16<<<dim3(32, 256), dim3(32, 8), 0, stream>>>(
        (const ushort*)Vb, (ushort*)VT, 8192, 1024);

    // 4) E = exp((Qi8 . Ki8)/41472), 16x16x64 i8 MFMA, grid 1024
    gemmEi8<<<1024, 512, 0, stream>>>(Qi8, Ki8, E, 1024, 1024, 8192, 32);

    // 5) inv[row] = 1 / rowsum(E)
    rowsum_inv<<<8192, 256, 0, stream>>>(E, invp, 8192);

    // 6) P = E @ VT^T, 16x16x32 bf16 (r10/r13-proven), split-K=2, grid 256
    gemmW<float, 256, 2, 0><<<256, 512, 0, stream>>>(E, VT, out, Pv,
                                                     nullptr, nullptr, nullptr,
                                                     4096, 8192, 8192, 1024, 4);

    // 7) out = (P0 + P1) * inv[row]
    add_scale<<<8192, 256, 0, stream>>>(out, Pv, invp, (8192 * 1024) / 4);
}

// Round 16
// 327.007 us; speedup vs baseline: 1.1394x; 1.0410x over previous
//
#include <hip/hip_runtime.h>
#include <hip/hip_bf16.h>
#include <stdint.h>
#include <math.h>

typedef __bf16 bf16;
typedef __bf16 bf16x8 __attribute__((ext_vector_type(8)));
typedef __bf16 bf16x4 __attribute__((ext_vector_type(4)));
typedef float  f32x4  __attribute__((ext_vector_type(4)));
typedef int    i32x4  __attribute__((ext_vector_type(4)));

#define AS_GLOBAL __attribute__((address_space(1)))
#define AS_LDS    __attribute__((address_space(3)))

__device__ __forceinline__ void gload_lds16(const void* g, void* l) {
    __builtin_amdgcn_global_load_lds((const AS_GLOBAL uint32_t*)g,
                                     (AS_LDS uint32_t*)l, 16, 0, 0);
}
__device__ __forceinline__ void cfence() { asm volatile("" ::: "memory"); }
#define BAR()    do { cfence(); __builtin_amdgcn_s_barrier(); cfence(); } while (0)
#define WAITV(n) asm volatile("s_waitcnt vmcnt(" #n ")" ::: "memory")
#define WAITL0() asm volatile("s_waitcnt lgkmcnt(0)" ::: "memory")

#define QSC 36.0f                            // q/k int8 scale
#define QDQ (1.0f / (QSC * QSC * 32.0f))     // logit dequant incl 1/sqrt(1024)

__device__ __forceinline__ int qi8(float f) {
    int q = (int)rintf(f);
    return q > 127 ? 127 : (q < -127 ? -127 : q);
}

// ---------------- convert fp32 -> bf16, 4 elems/thread ----------------
__global__ __launch_bounds__(256) void cvt_f32_to_bf16(const float* __restrict__ in,
                                                       bf16* __restrict__ out, int n4) {
    int i = blockIdx.x * 256 + threadIdx.x;
    if (i >= n4) return;
    const float4* p = (const float4*)in;
    float4 v = p[i];
    bf16x4 o;
    o[0] = (bf16)v.x; o[1] = (bf16)v.y; o[2] = (bf16)v.z; o[3] = (bf16)v.w;
    *(bf16x4*)(out + (size_t)i * 4) = o;
}

// ---------------- zero a float buffer ----------------
__global__ __launch_bounds__(256) void zero_f32(float* __restrict__ p, int n) {
    int i = blockIdx.x * 256 + threadIdx.x;
    if (i < n) p[i] = 0.f;
}

// ====== 2-window/K-tile bf16 GEMM (r7/r10/r13/r15 verified): C = A * B^T ======
// EPI=0: CT out (+split-K).  EPI=1: QKV projection epilogue (r15-verified) —
// col panel 0 -> Qi8 (int8 x36), 1 -> Ki8, 2 -> Vb bf16 compact (ld=1024).
template<typename CT, int BN, int SPLIT, int EPI>
__global__ __launch_bounds__(512, 2) void gemmW(const bf16* __restrict__ A,
                                                const bf16* __restrict__ B,
                                                CT* __restrict__ C,
                                                CT* __restrict__ C2,
                                                int8_t* __restrict__ q8,
                                                int8_t* __restrict__ k8,
                                                bf16* __restrict__ vb,
                                                int K, int lda, int ldb, int ldc,
                                                int nbn) {
    constexpr int NBH = BN / 128;
    constexpr int NR  = BN / 64;
    constexpr int NHF = NR / 2;
    __shared__ char smem[65536 + NBH * 32768];

    const int tid  = threadIdx.x;
    const int lane = tid & 63;
    const int wave = tid >> 6;
    const int wr   = wave >> 2;
    const int wc   = wave & 3;
    const int frow = lane & 15;
    const int fg   = lane >> 4;

    const int cpx = gridDim.x >> 3;
    const int swz = ((int)blockIdx.x & 7) * cpx + ((int)blockIdx.x >> 3);
    int id = swz, s = 0;
    if (SPLIT == 2) { s = id & 1; id >>= 1; }
    const int bm = id / nbn, bn = id % nbn;
    const int NT = K >> 6;
    const size_t koff = (size_t)s * K;
    CT* Cp = (SPLIT == 2 && s == 1) ? C2 : C;

    const int r0 = tid >> 3;
    const int c0 = ((tid & 7) ^ (r0 & 7)) << 3;
    const bf16* Abase = A + (size_t)(bm * 256 + r0) * lda + c0 + koff;
    const bf16* Bbase = B + (size_t)(bn * BN + r0) * ldb + c0 + koff;

    auto stA = [&](int t, int h) {
        char* d = smem + ((t & 1) << 15) + (h << 14) + (tid << 4);
        gload_lds16(Abase + ((size_t)(h * 128)      ) * lda + t * 64, d);
        gload_lds16(Abase + ((size_t)(h * 128) + 64 ) * lda + t * 64, d + 8192);
    };
    auto stB = [&](int t, int h) {
        char* d = smem + 65536 + (t & 1) * (NBH * 16384) + (h << 14) + (tid << 4);
        gload_lds16(Bbase + ((size_t)(h * 128)      ) * ldb + t * 64, d);
        gload_lds16(Bbase + ((size_t)(h * 128) + 64 ) * ldb + t * 64, d + 8192);
    };
    auto rdA = [&](int t, int m, int kk) -> bf16x8 {
        int r = m * 16 + frow;
        return *(const bf16x8*)(smem + ((t & 1) << 15) + (wr << 14)
                + r * 128 + ((((kk << 2) + fg) ^ (frow & 7)) << 4));
    };
    auto rdB = [&](int t, int n, int kk) -> bf16x8 {
        int br = wc * (BN / 4) + n * 16 + frow;
        return *(const bf16x8*)(smem + 65536 + (t & 1) * (NBH * 16384) + ((br >> 7) << 14)
                + (br & 127) * 128 + ((((kk << 2) + fg) ^ (frow & 7)) << 4));
    };

    f32x4 acc[8][NR] = {};
    bf16x8 aLo[4][2], aHi[4][2], bLo[NHF][2], bHi[NHF][2];

#define MMQ(MO, NO, AARR, BARR) \
    _Pragma("unroll") for (int m_ = 0; m_ < 4; ++m_) \
    _Pragma("unroll") for (int n_ = 0; n_ < NHF; ++n_) \
    _Pragma("unroll") for (int k_ = 0; k_ < 2; ++k_) \
        acc[m_ + MO][n_ + NO] = __builtin_amdgcn_mfma_f32_16x16x32_bf16( \
            AARR[m_][k_], BARR[n_][k_], acc[m_ + MO][n_ + NO], 0, 0, 0);

    stA(0, 0); stA(0, 1);
    stB(0, 0); if constexpr (NBH == 2) stB(0, 1);
    stA(1, 0); stA(1, 1);
    if constexpr (NBH == 2) { stB(1, 0); WAITV(6); } else { WAITV(4); }
    BAR();

    for (int t = 0; t < NT; ++t) {
        if (t + 1 < NT) stB(t + 1, NBH - 1);
        #pragma unroll
        for (int m_ = 0; m_ < 4; ++m_) { aLo[m_][0] = rdA(t, m_, 0); aLo[m_][1] = rdA(t, m_, 1); }
        #pragma unroll
        for (int n_ = 0; n_ < NHF; ++n_) { bLo[n_][0] = rdB(t, n_, 0); bLo[n_][1] = rdB(t, n_, 1); }
        #pragma unroll
        for (int n_ = 0; n_ < NHF; ++n_) { bHi[n_][0] = rdB(t, NHF + n_, 0); bHi[n_][1] = rdB(t, NHF + n_, 1); }
        #pragma unroll
        for (int m_ = 0; m_ < 4; ++m_) { aHi[m_][0] = rdA(t, 4 + m_, 0); aHi[m_][1] = rdA(t, 4 + m_, 1); }
        __builtin_amdgcn_s_setprio(1);
        MMQ(0, 0, aLo, bLo);
        MMQ(0, NHF, aLo, bHi);
        __builtin_amdgcn_s_setprio(0);
        WAITL0();
        BAR();
        if (t + 2 < NT) {
            stA(t + 2, 0); stA(t + 2, 1);
            if constexpr (NBH == 2) stB(t + 2, 0);
        }
        __builtin_amdgcn_s_setprio(1);
        MMQ(4, NHF, aHi, bHi);
        MMQ(4, 0, aHi, bLo);
        __builtin_amdgcn_s_setprio(0);
        if (t + 2 < NT) {
            if constexpr (NBH == 2) WAITV(6); else WAITV(4);
        } else if (t + 1 < NT) {
            WAITV(0);
        }
        BAR();
    }
#undef MMQ

    const size_t crow0 = (size_t)bm * 256 + wr * 128 + (fg << 2);
    const size_t ccol0 = (size_t)bn * BN + wc * (BN / 4) + frow;
    if constexpr (EPI == 1) {
        const int panel = (int)(ccol0 >> 10);            // 0=Q, 1=K, 2=V
        const size_t pcol0 = ccol0 & 1023;
        #pragma unroll
        for (int m = 0; m < 8; ++m)
            #pragma unroll
            for (int n = 0; n < NR; ++n)
                #pragma unroll
                for (int i = 0; i < 4; ++i) {
                    float v = acc[m][n][i];
                    size_t row = crow0 + m * 16 + i;
                    size_t col = pcol0 + n * 16;
                    if (panel == 0)
                        q8[row * 1024 + col] = (int8_t)qi8(v * QSC);
                    else if (panel == 1)
                        k8[row * 1024 + col] = (int8_t)qi8(v * QSC);
                    else
                        vb[row * 1024 + col] = (bf16)v;
                }
    } else {
        #pragma unroll
        for (int m = 0; m < 8; ++m)
            #pragma unroll
            for (int n = 0; n < NR; ++n)
                #pragma unroll
                for (int i = 0; i < 4; ++i)
                    Cp[(crow0 + m * 16 + i) * ldc + ccol0 + n * 16] = (CT)(acc[m][n][i]);
    }
}

// ====== int8 QK^T -> bf16 E = exp(acc/41472), 16x16x64 i8 MFMA (r13 verified) ======
// + fused row-sum via LDS (r11 lesson: NO shuffles — ds_bpermute storm).
// After the main loop, LDS is dead: each lane writes 32 n-summed partials into
// padded part[256][66] (<=2-way write conflicts = free, m136), one barrier,
// 256 threads reduce 64 entries each, one atomicAdd per row per block.
__global__ __launch_bounds__(512, 2) void gemmEi8(const int8_t* __restrict__ A,
                                                  const int8_t* __restrict__ B,
                                                  bf16* __restrict__ E,
                                                  float* __restrict__ sums,
                                                  int K, int ld, int ldc, int nbn) {
    __shared__ char smem[131072];   // A dbuf 2x32KB @0 | B dbuf 2x32KB @65536

    const int tid  = threadIdx.x;
    const int lane = tid & 63;
    const int wave = tid >> 6;
    const int wr   = wave >> 2;           // 0..1
    const int wc   = wave & 3;            // 0..3
    const int frow = lane & 15;
    const int fg   = lane >> 4;           // 0..3

    const int cpx = gridDim.x >> 3;
    const int swz = ((int)blockIdx.x & 7) * cpx + ((int)blockIdx.x >> 3);
    const int bm = swz / nbn, bn = swz % nbn;
    const int NT = K >> 7;                // 8

    const int r0 = tid >> 3;
    const int c0 = ((tid & 7) ^ (r0 & 7)) << 4;     // inv-swizzled byte col
    const int8_t* Abase = A + (size_t)(bm * 256 + r0) * ld + c0;
    const int8_t* Bbase = B + (size_t)(bn * 256 + r0) * ld + c0;

    auto stA = [&](int t, int h) {
        char* d = smem + ((t & 1) << 15) + (h << 14) + (tid << 4);
        gload_lds16(Abase + ((size_t)(h * 128)     ) * ld + t * 128, d);
        gload_lds16(Abase + ((size_t)(h * 128) + 64) * ld + t * 128, d + 8192);
    };
    auto stB = [&](int t, int h) {
        char* d = smem + 65536 + ((t & 1) << 15) + (h << 14) + (tid << 4);
        gload_lds16(Bbase + ((size_t)(h * 128)     ) * ld + t * 128, d);
        gload_lds16(Bbase + ((size_t)(h * 128) + 64) * ld + t * 128, d + 8192);
    };
    auto rdA = [&](int t, int m, int kk) -> i32x4 {   // m in [0,8)
        int r = m * 16 + frow;
        return *(const i32x4*)(smem + ((t & 1) << 15) + (wr << 14)
                + r * 128 + ((((kk << 2) + fg) ^ (frow & 7)) << 4));
    };
    auto rdB = [&](int t, int n, int kk) -> i32x4 {   // n in [0,4)
        int br = wc * 64 + n * 16 + frow;
        return *(const i32x4*)(smem + 65536 + ((t & 1) << 15) + ((br >> 7) << 14)
                + (br & 127) * 128 + ((((kk << 2) + fg) ^ (frow & 7)) << 4));
    };

    i32x4 acc[8][4] = {};
    i32x4 aLo[4][2], aHi[4][2], bLo[2][2], bHi[2][2];

#define MMQ(MO, NO, AARR, BARR) \
    _Pragma("unroll") for (int m_ = 0; m_ < 4; ++m_) \
    _Pragma("unroll") for (int n_ = 0; n_ < 2; ++n_) \
    _Pragma("unroll") for (int k_ = 0; k_ < 2; ++k_) \
        acc[m_ + MO][n_ + NO] = __builtin_amdgcn_mfma_i32_16x16x64_i8( \
            AARR[m_][k_], BARR[n_][k_], acc[m_ + MO][n_ + NO], 0, 0, 0);

    stA(0, 0); stA(0, 1);
    stB(0, 0); stB(0, 1);
    stA(1, 0); stA(1, 1);
    stB(1, 0); WAITV(6);
    BAR();

    for (int t = 0; t < NT; ++t) {
        if (t + 1 < NT) stB(t + 1, 1);
        #pragma unroll
        for (int m_ = 0; m_ < 4; ++m_) { aLo[m_][0] = rdA(t, m_, 0); aLo[m_][1] = rdA(t, m_, 1); }
        #pragma unroll
        for (int n_ = 0; n_ < 2; ++n_) { bLo[n_][0] = rdB(t, n_, 0); bLo[n_][1] = rdB(t, n_, 1); }
        #pragma unroll
        for (int n_ = 0; n_ < 2; ++n_) { bHi[n_][0] = rdB(t, 2 + n_, 0); bHi[n_][1] = rdB(t, 2 + n_, 1); }
        #pragma unroll
        for (int m_ = 0; m_ < 4; ++m_) { aHi[m_][0] = rdA(t, 4 + m_, 0); aHi[m_][1] = rdA(t, 4 + m_, 1); }
        __builtin_amdgcn_s_setprio(1);
        MMQ(0, 0, aLo, bLo);
        MMQ(0, 2, aLo, bHi);
        __builtin_amdgcn_s_setprio(0);
        WAITL0();
        BAR();
        if (t + 2 < NT) { stA(t + 2, 0); stA(t + 2, 1); stB(t + 2, 0); }
        __builtin_amdgcn_s_setprio(1);
        MMQ(4, 2, aHi, bHi);
        MMQ(4, 0, aHi, bLo);
        __builtin_amdgcn_s_setprio(0);
        if (t + 2 < NT)      { WAITV(6); }
        else if (t + 1 < NT) { WAITV(0); }
        BAR();
    }
#undef MMQ

    // epilogue: E = exp(acc * QDQ) + LDS row-partial reduction
    const size_t crow0 = (size_t)bm * 256 + wr * 128 + (fg << 2);
    const size_t ccol0 = (size_t)bn * 256 + wc * 64 + frow;
    float* part = (float*)smem;                 // [256][66] floats = 67.6 KB
    const int rl0 = wr * 128 + (fg << 2);       // local row base
    const int ent = wc * 16 + frow;             // 0..63 entry slot
    #pragma unroll
    for (int m = 0; m < 8; ++m)
        #pragma unroll
        for (int i = 0; i < 4; ++i) {
            float s = 0.f;
            #pragma unroll
            for (int n = 0; n < 4; ++n) {
                float e = __expf((float)acc[m][n][i] * QDQ);
                bf16 b = (bf16)e;
                E[(crow0 + m * 16 + i) * ldc + ccol0 + n * 16] = b;
                s += (float)b;
            }
            part[(rl0 + m * 16 + i) * 66 + ent] = s;
        }
    __syncthreads();
    if (tid < 256) {
        float s = 0.f;
        const float* pr = part + tid * 66;
        #pragma unroll 8
        for (int e = 0; e < 64; ++e) s += pr[e];
        atomicAdd(&sums[(size_t)bm * 256 + tid], s);
    }
}

// ------- out[i] = (out[i] + part[i]) / sums[row], float4 -------
__global__ __launch_bounds__(256) void add_scale(float* __restrict__ out,
                                                 const float* __restrict__ part,
                                                 const float* __restrict__ sums, int n4) {
    int i = blockIdx.x * 256 + threadIdx.x;
    if (i >= n4) return;
    const float sc = 1.0f / sums[i >> 8];
    float4 a = ((const float4*)out)[i];
    float4 b = ((const float4*)part)[i];
    a.x = (a.x + b.x) * sc; a.y = (a.y + b.y) * sc;
    a.z = (a.z + b.z) * sc; a.w = (a.w + b.w) * sc;
    ((float4*)out)[i] = a;
}

// ------- bf16 transpose with input row stride: VT[c][r] = V[r*ld + c] -------
__global__ __launch_bounds__(256) void transpose_bf16(const ushort* __restrict__ V,
                                                      ushort* __restrict__ VT,
                                                      int R, int ld) {
    __shared__ ushort tile[32][33];
    const int tx = threadIdx.x, ty = threadIdx.y;
    const int r0 = blockIdx.y * 32, c0 = blockIdx.x * 32;
    #pragma unroll
    for (int i = 0; i < 32; i += 8)
        tile[ty + i][tx] = V[(size_t)(r0 + ty + i) * ld + c0 + tx];
    __syncthreads();
    #pragma unroll
    for (int i = 0; i < 32; i += 8)
        VT[(size_t)(c0 + ty + i) * R + r0 + tx] = tile[tx][ty + i];
}

extern "C" void kernel_launch(void* const* d_in, const int* in_sizes, int n_in,
                              void* d_out, int out_size, void* d_ws, size_t ws_size,
                              hipStream_t stream) {
    const float* h  = (const float*)d_in[0];
    const float* wq = (const float*)d_in[1];
    const float* wk = (const float*)d_in[2];
    const float* wv = (const float*)d_in[3];
    float* out = (float*)d_out;

    char* ws = (char*)d_ws;
    bf16*   h_bf = (bf16*)(ws);                         // 16 MB [8192 x 1024]
    bf16*   wcat = (bf16*)(ws + (16ull << 20));         //  6 MB [3072 x 1024]
    int8_t* Qi8  = (int8_t*)(ws + (22ull << 20));       //  8 MB [8192 x 1024]
    int8_t* Ki8  = (int8_t*)(ws + (30ull << 20));       //  8 MB
    bf16*   Vb   = (bf16*)(ws + (38ull << 20));         // 16 MB [8192 x 1024]
    bf16*   VT   = (bf16*)(ws + (54ull << 20));         // 16 MB [1024 x 8192]
    bf16*   E    = (bf16*)(ws + (70ull << 20));         // 128 MB [8192 x 8192]
    float*  Pv   = (float*)(ws);                        // 32 MB (h_bf..Ki8 dead by PV)
    float*  sums = (float*)(ws + (198ull << 20));       // 32 KB

    // 1) inputs -> bf16 (weights concatenated [3072,1024]); zero row-sum acc
    cvt_f32_to_bf16<<<8192, 256, 0, stream>>>(h,  h_bf, (8192 * 1024) / 4);
    cvt_f32_to_bf16<<<1024, 256, 0, stream>>>(wq, wcat,               (1024 * 1024) / 4);
    cvt_f32_to_bf16<<<1024, 256, 0, stream>>>(wk, wcat + 1024 * 1024, (1024 * 1024) / 4);
    cvt_f32_to_bf16<<<1024, 256, 0, stream>>>(wv, wcat + 2048 * 1024, (1024 * 1024) / 4);
    zero_f32<<<32, 256, 0, stream>>>(sums, 8192);

    // 2) fused QKV projection: Q,K -> int8 (scale 36), V -> compact bf16, grid 384
    gemmW<bf16, 256, 1, 1><<<384, 512, 0, stream>>>(h_bf, wcat, nullptr, nullptr,
                                                    Qi8, Ki8, Vb,
                                                    1024, 1024, 1024, 1024, 12);

    // 3) VT = Vb^T (ld = 1024)
    transpose_bf16<<<dim3(32, 256), dim3(32, 8), 0, stream>>>(
        (const ushort*)Vb, (ushort*)VT, 8192, 1024);

    // 4) E = exp((Qi8 . Ki8)/41472) + fused LDS row-sums, grid 1024
    gemmEi8<<<1024, 512, 0, stream>>>(Qi8, Ki8, E, sums, 1024, 1024, 8192, 32);

    // 5) P = E @ VT^T, 16x16x32 bf16 (r10/r13-proven), split-K=2, grid 256
    gemmW<float, 256, 2, 0><<<256, 512, 0, stream>>>(E, VT, out, Pv,
                                                     nullptr, nullptr, nullptr,
                                                     4096, 8192, 8192, 1024, 4);

    // 6) out = (P0 + P1) / sums[row]
    add_scale<<<8192, 256, 0, stream>>>(out, Pv, sums, (8192 * 1024) / 4);
}